// Round 4
// baseline (640.152 us; speedup 1.0000x reference)
//
#include <hip/hip_runtime.h>
#include <math.h>

#define BB 4
#define TT 10
#define NN 4096
#define HH 32
#define JP 144                    // padded j (132 real: 4 b * 33 kk)
#define NJ2 (NN*JP)               // 589824
#define NH (NN*HH)                // 131072
#define NPAIR (NN*NN/2)           // 8388608 (fp16 pairs / u32 words)

typedef __attribute__((ext_vector_type(8))) short short8;
typedef __attribute__((ext_vector_type(8))) _Float16 half8;
typedef __attribute__((ext_vector_type(4))) float floatx4;
typedef __attribute__((ext_vector_type(4))) unsigned int uintx4;
typedef __attribute__((ext_vector_type(2))) unsigned int uintx2;

__device__ inline unsigned short f2h(float f) {
    _Float16 h = (_Float16)f;                  // v_cvt_f16_f32, RNE
    unsigned short u; __builtin_memcpy(&u, &h, 2);
    return u;
}
__device__ inline unsigned pk2(float a, float b) {
    return (unsigned)f2h(a) | ((unsigned)f2h(b) << 16);
}

// ---------- prep: pack A_off=spl+I, A_on=off+dtw, A9=off+masked dtw+lap, thr u8 ----------
__global__ void k_pack(const float* __restrict__ dtw, const float* __restrict__ tdl,
                       const float* __restrict__ spl, const float* __restrict__ lap,
                       unsigned* __restrict__ Aoff, unsigned* __restrict__ Aon,
                       unsigned* __restrict__ A9, unsigned short* __restrict__ thr2) {
    int e = blockIdx.x * 256 + threadIdx.x;          // pair index
    if (e >= NPAIR) return;
    size_t gi = (size_t)e * 2;
    int row = (int)(gi >> 12);
    int c0 = (int)(gi & 4095);
    float2 d = ((const float2*)dtw)[e];
    float2 td = ((const float2*)tdl)[e];
    float2 s = ((const float2*)spl)[e];
    float2 l = ((const float2*)lap)[e];
    float td0 = ceilf(fabsf(td.x)), td1 = ceilf(fabsf(td.y));
    int th0 = 10 - (int)td0; if (th0 < 0) th0 = 0;
    int th1 = 10 - (int)td1; if (th1 < 0) th1 = 0;
    float off0 = s.x + ((row == c0) ? 1.f : 0.f);
    float off1 = s.y + ((row == c0 + 1) ? 1.f : 0.f);
    float on0 = off0 + d.x, on1 = off1 + d.y;
    // t=9 mask: t+1=10 > 10-td_c  <=>  td_c>0 ; plus dtw!=0 exactness
    float a90 = off0 + l.x + ((td0 > 0.f && d.x != 0.f) ? d.x : 0.f);
    float a91 = off1 + l.y + ((td1 > 0.f && d.y != 0.f) ? d.y : 0.f);
    Aoff[e] = pk2(off0, off1);
    Aon[e]  = pk2(on0, on1);
    A9[e]   = pk2(a90, a91);
    thr2[e] = (unsigned short)(th0 | (th1 << 8));
}

// ---------- build Ct[t][j][n] fp16, scale folded; pass1 (h raw); also zero pad rows ----------
__global__ void k_build_ct1(const float* __restrict__ inp, const float* __restrict__ st,
                            unsigned short* __restrict__ Ct) {
    int nb = blockIdx.x, b = blockIdx.y, t = blockIdx.z;
    int tid = threadIdx.x;
    float sc = (t == TT - 1) ? (1.f / 3.f) : 0.5f;
    int kk = tid & 31;          // channel 0..31 -> j = b*33 + 1 + kk
    int ng = tid >> 5;          // 0..7
    const float* stb = st + (size_t)(t * BB + b) * NH;
    unsigned short* crow = Ct + (size_t)(t * JP + b * 33 + 1 + kk) * NN;
    int n0 = nb * 128 + ng * 16;
#pragma unroll
    for (int i = 0; i < 16; i++) {
        int n = n0 + i;
        crow[n] = f2h(stb[n * 32 + kk] * sc);       // coalesced read across kk
    }
    if (tid < 128) {            // x row: j = b*33
        int n = nb * 128 + tid;
        Ct[(size_t)(t * JP + b * 33) * NN + n] = f2h(inp[((size_t)b * TT + t) * NN + n] * sc);
        // pad rows 132..143: each b-block zeroes 3 of the 12
#pragma unroll
        for (int rr = 0; rr < 3; rr++)
            Ct[(size_t)(t * JP + 132 + b * 3 + rr) * NN + n] = 0;
    }
}

// ---------- build Ct pass2: h replaced by r*h, r = sigmoid(gcn1 flat); also zero pad ----------
__global__ void k_build_ct2(const float* __restrict__ inp, const float* __restrict__ st,
                            const float* __restrict__ G, unsigned short* __restrict__ Ct) {
    int nb = blockIdx.x, b = blockIdx.y, t = blockIdx.z;
    int tid = threadIdx.x;
    float sc = (t == TT - 1) ? (1.f / 3.f) : 0.5f;
    int kk = tid & 31;
    int ng = tid >> 5;
    const float* stb = st + (size_t)(t * BB + b) * NH;
    const float* Gb = G + (size_t)(t * BB + b) * NN * 64;   // flat index == jj
    unsigned short* crow = Ct + (size_t)(t * JP + b * 33 + 1 + kk) * NN;
    int n0 = nb * 128 + ng * 16;
#pragma unroll
    for (int i = 0; i < 16; i++) {
        int n = n0 + i;
        int jj = n * 32 + kk;
        float g = Gb[jj];
        float r = 1.0f / (1.0f + expf(-g));
        crow[n] = f2h(r * stb[jj] * sc);
    }
    if (tid < 128) {
        int n = nb * 128 + tid;
        Ct[(size_t)(t * JP + b * 33) * NN + n] = f2h(inp[((size_t)b * TT + t) * NN + n] * sc);
#pragma unroll
        for (int rr = 0; rr < 3; rr++)
            Ct[(size_t)(t * JP + 132 + b * 3 + rr) * NN + n] = 0;
    }
}

// ---------- MFMA GEMM: Out[ks][t][m][j] = sum_{k in split} A_t[m,k] * C_t[k,j] ----------
// Flat grid, f = t*64 + g so the 10 t-siblings of one (m,ks) A-slice share f%8 -> same XCD L2.
__global__ __launch_bounds__(256) void k_mfma(const unsigned* __restrict__ Aoff,
                                              const unsigned* __restrict__ Aon,
                                              const unsigned* __restrict__ A9,
                                              const unsigned short* __restrict__ thr2,
                                              const unsigned* __restrict__ Ct,
                                              float* __restrict__ Out) {
    int f = blockIdx.x;
    int t = f >> 6;               // 0..9
    int g = f & 63;               // (m,ks) group
    int m0 = (g >> 1) * 128;
    int ks = g & 1;
    int k0 = ks * 2048;
    int tid = threadIdx.x;
    int w = tid >> 6, lane = tid & 63;
    int lm = lane & 15, q = lane >> 4;

    __shared__ short As[128 * 40];     // row stride 40 shorts (80B), A_t tile [m][k]
    __shared__ short Cs[JP * 40];      // [j][k]
    unsigned* Asu = (unsigned*)As;
    unsigned* Csu = (unsigned*)Cs;

    floatx4 acc[2][9];
#pragma unroll
    for (int i = 0; i < 2; i++)
#pragma unroll
        for (int j = 0; j < 9; j++) acc[i][j] = (floatx4){0.f, 0.f, 0.f, 0.f};

    bool last = (t == TT - 1);

    int row0 = tid >> 2, c4 = (tid & 3) * 4;
    size_t cb = (size_t)t * JP;

    // prefetch registers
    uintx4 rO0, rO1, rN0, rN1, rC0, rC1, rC2;
    uintx2 rT0, rT1;

#define LOAD_CHUNK(KB)                                                              \
    do {                                                                            \
        size_t kc = (size_t)(k0 + (KB)) >> 1;                                       \
        size_t g0 = (size_t)(m0 + row0) * 2048 + kc + c4;                           \
        size_t g1 = g0 + (size_t)64 * 2048;                                         \
        if (last) {                                                                 \
            rO0 = *(const uintx4*)(A9 + g0);                                        \
            rO1 = *(const uintx4*)(A9 + g1);                                        \
        } else {                                                                    \
            rO0 = *(const uintx4*)(Aoff + g0);                                      \
            rO1 = *(const uintx4*)(Aoff + g1);                                      \
            rN0 = *(const uintx4*)(Aon + g0);                                       \
            rN1 = *(const uintx4*)(Aon + g1);                                       \
            rT0 = *(const uintx2*)(thr2 + g0);                                      \
            rT1 = *(const uintx2*)(thr2 + g1);                                      \
        }                                                                           \
        rC0 = *(const uintx4*)(Ct + (cb + row0) * 2048 + kc + c4);                  \
        rC1 = *(const uintx4*)(Ct + (cb + row0 + 64) * 2048 + kc + c4);             \
        if (tid < 64) rC2 = *(const uintx4*)(Ct + (cb + row0 + 128) * 2048 + kc + c4); \
    } while (0)

    LOAD_CHUNK(0);

    for (int kb = 0; kb < 2048; kb += 32) {
        // ---- stage prefetched regs -> LDS (A select happens here)
#pragma unroll
        for (int it = 0; it < 2; it++) {
            int row = row0 + it * 64;
            uintx4 res;
            if (last) {
                res = it ? rO1 : rO0;
            } else {
                uintx4 o4 = it ? rO1 : rO0;
                uintx4 a4 = it ? rN1 : rN0;
                uintx2 th2 = it ? rT1 : rT0;
#pragma unroll
                for (int u = 0; u < 4; u++) {
                    unsigned th = (u < 2) ? (th2[0] >> ((u & 1) * 16)) : (th2[1] >> ((u & 1) * 16));
                    th &= 0xFFFFu;
                    unsigned lo = ((int)(th & 255u) <= t) ? a4[u] : o4[u];
                    unsigned hi = ((int)(th >> 8) <= t) ? a4[u] : o4[u];
                    res[u] = (lo & 0xFFFFu) | (hi & 0xFFFF0000u);
                }
            }
            *(uintx4*)(Asu + row * 20 + c4) = res;
        }
        *(uintx4*)(Csu + row0 * 20 + c4) = rC0;
        *(uintx4*)(Csu + (row0 + 64) * 20 + c4) = rC1;
        if (tid < 64) *(uintx4*)(Csu + (row0 + 128) * 20 + c4) = rC2;
        __syncthreads();

        // ---- issue next chunk's global loads now; they fly during the MFMA section
        if (kb + 32 < 2048) LOAD_CHUNK(kb + 32);

        // ---- fragments + MFMA: wave w -> rows [w*32, w*32+32), all 9 j-tiles
        short8 a0 = *(const short8*)(As + (w * 32 + lm) * 40 + q * 8);
        short8 a1 = *(const short8*)(As + (w * 32 + 16 + lm) * 40 + q * 8);
        half8 ah0 = __builtin_bit_cast(half8, a0);
        half8 ah1 = __builtin_bit_cast(half8, a1);
#pragma unroll
        for (int jt = 0; jt < 9; jt++) {
            short8 bv = *(const short8*)(Cs + (jt * 16 + lm) * 40 + q * 8);
            half8 bh = __builtin_bit_cast(half8, bv);
            acc[0][jt] = __builtin_amdgcn_mfma_f32_16x16x32_f16(ah0, bh, acc[0][jt], 0, 0, 0);
            acc[1][jt] = __builtin_amdgcn_mfma_f32_16x16x32_f16(ah1, bh, acc[1][jt], 0, 0, 0);
        }
        __syncthreads();
    }
#undef LOAD_CHUNK

    // ---- epilogue: C/D layout col=lane&15, row=(lane>>4)*4+r
    float* Ob = Out + ((size_t)ks * TT + t) * (size_t)NN * JP;
#pragma unroll
    for (int mt = 0; mt < 2; mt++) {
        int row = m0 + w * 32 + mt * 16 + q * 4;
#pragma unroll
        for (int jt = 0; jt < 9; jt++) {
            int col = jt * 16 + lm;
#pragma unroll
            for (int r = 0; r < 4; r++)
                Ob[(size_t)(row + r) * JP + col] = acc[mt][jt][r];
        }
    }
}

// ---------- prefix sum over t (reads both k-splits, writes prefix into O0) ----------
__global__ void k_prefix(float* __restrict__ O0, const float* __restrict__ O1) {
    int e = blockIdx.x * 256 + threadIdx.x;
    if (e >= NJ2) return;
    float run = 0.f;
#pragma unroll
    for (int t = 0; t < TT; t++) {
        run += O0[(size_t)t * NJ2 + e] + O1[(size_t)t * NJ2 + e];
        O0[(size_t)t * NJ2 + e] = run;
    }
}

// ---------- gcn1[t][b][m][q] = (t+1)*b1[q] + sum_kk P[t][m][b*33+kk]*W1[kk][q] ----------
__global__ __launch_bounds__(256) void k_gcn1(const float* __restrict__ P,
                                              const float* __restrict__ W1,
                                              const float* __restrict__ b1,
                                              float* __restrict__ G) {
    int m0 = blockIdx.x * 32;
    int b = blockIdx.y, t = blockIdx.z;
    int tid = threadIdx.x;
    __shared__ float Ws[33 * 64];
    __shared__ float Ps[32 * 33];
    for (int l = tid; l < 33 * 64; l += 256) Ws[l] = W1[l];
    for (int l = tid; l < 32 * 33; l += 256) {
        int mr = l / 33, kk = l - mr * 33;
        Ps[l] = P[(size_t)(t * NN + m0 + mr) * JP + b * 33 + kk];
    }
    __syncthreads();
    int qq = tid & 63, ms = tid >> 6;
    float bias = (float)(t + 1) * b1[qq];
    for (int mi = 0; mi < 8; mi++) {
        int ml = ms * 8 + mi;
        float a = bias;
#pragma unroll
        for (int kk = 0; kk < 33; kk++) a = fmaf(Ps[ml * 33 + kk], Ws[kk * 64 + qq], a);
        G[(size_t)((t * BB + b) * NN + m0 + ml) * 64 + qq] = a;
    }
}

// ---------- reduce over t (both splits) -> S[m][JP] ----------
__global__ void k_reduce(const float* __restrict__ O0, const float* __restrict__ O1,
                         float* __restrict__ S) {
    int e = blockIdx.x * 256 + threadIdx.x;
    if (e >= NJ2) return;
    float s = 0.f;
#pragma unroll
    for (int t = 0; t < TT; t++)
        s += O0[(size_t)t * NJ2 + e] + O1[(size_t)t * NJ2 + e];
    S[e] = s;
}

// ---------- epilogue: gcn2@W2 + bias, tanh, u-gate ----------
__global__ __launch_bounds__(256) void k_final(const float* __restrict__ S,
                                               const float* __restrict__ G,
                                               const float* __restrict__ st,
                                               const float* __restrict__ W2,
                                               const float* __restrict__ b2,
                                               float* __restrict__ out) {
    __shared__ float Ws[33 * 32];
    int tid = threadIdx.x;
    for (int l = tid; l < 33 * 32; l += 256) Ws[l] = W2[l];
    __syncthreads();
    int e = blockIdx.x * 256 + tid;        // over B*N*H
    int b = e >> 17;
    int jj = e & (NH - 1);
    int m = jj >> 5, q = jj & 31;
    float a = 10.0f * b2[q];
#pragma unroll
    for (int kk = 0; kk < 33; kk++) a = fmaf(S[m * JP + b * 33 + kk], Ws[kk * 32 + q], a);
    float c = tanhf(a);
    float gu = G[(size_t)((9 * BB + b) * NN + 2048 + (jj >> 6)) * 64 + (jj & 63)];
    float u = 1.0f / (1.0f + expf(-gu));
    float h = st[(size_t)(9 * BB + b) * NH + jj];
    out[e] = u * h + (1.0f - u) * c;
}

extern "C" void kernel_launch(void* const* d_in, const int* in_sizes, int n_in,
                              void* d_out, int out_size, void* d_ws, size_t ws_size,
                              hipStream_t stream) {
    const float* inp = (const float*)d_in[0];
    const float* st  = (const float*)d_in[1];
    const float* dtw = (const float*)d_in[2];
    const float* spl = (const float*)d_in[3];
    const float* lap = (const float*)d_in[4];
    const float* tdl = (const float*)d_in[5];
    const float* W1  = (const float*)d_in[6];
    const float* b1  = (const float*)d_in[7];
    const float* W2  = (const float*)d_in[8];
    const float* b2  = (const float*)d_in[9];
    float* out = (float*)d_out;

    char* W = (char*)d_ws;
    unsigned*       Aoff = (unsigned*)W;                     W += (size_t)NPAIR * 4;
    unsigned*       Aon  = (unsigned*)W;                     W += (size_t)NPAIR * 4;
    unsigned*       A9   = (unsigned*)W;                     W += (size_t)NPAIR * 4;
    unsigned short* thr2 = (unsigned short*)W;               W += (size_t)NPAIR * 2;
    unsigned short* Ct   = (unsigned short*)W;               W += (size_t)TT * JP * NN * 2;
    float*          O    = (float*)W;                        W += (size_t)2 * TT * NJ2 * 4;
    float*          G    = (float*)W;                        W += (size_t)TT * BB * NN * 64 * 4;
    float*          S    = (float*)W;                        W += (size_t)NJ2 * 4;
    float* O1 = O + (size_t)TT * NJ2;

    k_pack<<<NPAIR / 256, 256, 0, stream>>>(dtw, tdl, spl, lap, Aoff, Aon, A9, thr2);

    dim3 gbld(NN / 128, BB, TT);
    k_build_ct1<<<gbld, 256, 0, stream>>>(inp, st, Ct);

    k_mfma<<<640, 256, 0, stream>>>(Aoff, Aon, A9, thr2, (const unsigned*)Ct, O);   // pass 1

    k_prefix<<<NJ2 / 256, 256, 0, stream>>>(O, O1);

    dim3 ggcn(NN / 32, BB, TT);
    k_gcn1<<<ggcn, 256, 0, stream>>>(O, W1, b1, G);

    k_build_ct2<<<gbld, 256, 0, stream>>>(inp, st, G, Ct);

    k_mfma<<<640, 256, 0, stream>>>(Aoff, Aon, A9, thr2, (const unsigned*)Ct, O);   // pass 2

    k_reduce<<<NJ2 / 256, 256, 0, stream>>>(O, O1, S);

    k_final<<<(BB * NN * HH) / 256, 256, 0, stream>>>(S, G, st, W2, b2, out);
}